// Round 1
// baseline (212.459 us; speedup 1.0000x reference)
//
#include <hip/hip_runtime.h>

#define DM   1024
#define LSEQ 1024
#define BATCH 8
#define MROWS (BATCH*LSEQ)   // 8192

typedef __attribute__((ext_vector_type(8))) short  bf16x8;
typedef __attribute__((ext_vector_type(4))) float  f32x4;
typedef __attribute__((ext_vector_type(4))) unsigned short u16x4;
typedef __attribute__((ext_vector_type(8))) unsigned short u16x8;

__device__ inline unsigned short f2bf(float f){
  unsigned u = __builtin_bit_cast(unsigned, f);
  u += 0x7fffu + ((u >> 16) & 1u);          // RNE
  return (unsigned short)(u >> 16);
}

__device__ inline void gload_lds16(const void* g, void* l){
  __builtin_amdgcn_global_load_lds(
      (const __attribute__((address_space(1))) void*)g,
      (__attribute__((address_space(3))) void*)l,
      16, 0, 0);
}

// stage a 128x32 bf16 tile (src leading dim = 1024) into linear LDS [128][32]
__device__ inline void stage_gload(const unsigned short* src, int row0, int k0,
                                   unsigned short* lds, int wave, int lane)
{
  #pragma unroll
  for (int it = 0; it < 2; ++it){
    int rowblk = (it*4 + wave) * 16;                 // wave-uniform
    int row = rowblk + (lane >> 2);
    int col = (lane & 3) * 8;
    gload_lds16(src + (size_t)(row0 + row)*1024 + k0 + col, lds + rowblk*32);
  }
}

// one BK=32 step: 4 A-frags, 4 B-frags, 16 MFMAs
__device__ inline void mma_step(const unsigned short* As, int lda,
                                const unsigned short* Bs, int ldb,
                                int wrb, int wcb, int fr, int kg,
                                f32x4 acc[4][4])
{
  bf16x8 av[4], bv[4];
  #pragma unroll
  for (int mi = 0; mi < 4; ++mi)
    av[mi] = *(const bf16x8*)(As + (size_t)(wrb + mi*16 + fr)*lda + kg*8);
  #pragma unroll
  for (int ni = 0; ni < 4; ++ni)
    bv[ni] = *(const bf16x8*)(Bs + (size_t)(wcb + ni*16 + fr)*ldb + kg*8);
  #pragma unroll
  for (int mi = 0; mi < 4; ++mi)
    #pragma unroll
    for (int ni = 0; ni < 4; ++ni)
      acc[mi][ni] = __builtin_amdgcn_mfma_f32_16x16x32_bf16(av[mi], bv[ni], acc[mi][ni], 0, 0, 0);
}

// ---------------- W transpose + convert:  Wt[n][k] = bf16(W[k][n]) ----------------
__global__ __launch_bounds__(256) void k_transpose_w(
    const float* __restrict__ W0, const float* __restrict__ W1, const float* __restrict__ W2,
    unsigned short* __restrict__ T0, unsigned short* __restrict__ T1, unsigned short* __restrict__ T2)
{
  __shared__ unsigned short tile[64*68];
  int z = blockIdx.z;
  const float* W = z==0 ? W0 : (z==1 ? W1 : W2);
  unsigned short* T = z==0 ? T0 : (z==1 ? T1 : T2);
  int n0 = blockIdx.x*64, k0 = blockIdx.y*64;
  int tid = threadIdx.x;
  {
    int r = tid >> 4;                 // 0..15
    int c = (tid & 15) * 4;
    #pragma unroll
    for (int it = 0; it < 4; ++it){
      f32x4 v = *(const f32x4*)(W + (size_t)(k0 + it*16 + r)*DM + n0 + c);
      u16x4 h; h[0]=f2bf(v[0]); h[1]=f2bf(v[1]); h[2]=f2bf(v[2]); h[3]=f2bf(v[3]);
      *(u16x4*)(tile + (it*16 + r)*68 + c) = h;
    }
  }
  __syncthreads();
  {
    int nl = tid >> 2;                // 0..63
    int kc = (tid & 3) * 16;
    u16x8 o;
    #pragma unroll
    for (int j = 0; j < 8; ++j) o[j] = tile[(kc+j)*68 + nl];
    *(u16x8*)(T + (size_t)(n0+nl)*DM + k0 + kc) = o;
    #pragma unroll
    for (int j = 0; j < 8; ++j) o[j] = tile[(kc+8+j)*68 + nl];
    *(u16x8*)(T + (size_t)(n0+nl)*DM + k0 + kc + 8) = o;
  }
}

// ---------------- projection GEMM: out = bf16( X_fp32 @ W )  ----------------
// z=0 -> q [B][L][D], z=1 -> k [B][L][D], z=2 -> vT [B][D][L] (transposed store)
#define SA 40           // padded A stride (bf16 elems), keeps 16B alignment, kills read conflicts
#define TS 136          // transpose-tile stride

__global__ __launch_bounds__(256) void k_proj(
    const float* __restrict__ X0, const float* __restrict__ X1, const float* __restrict__ X2,
    const unsigned short* __restrict__ W0, const unsigned short* __restrict__ W1, const unsigned short* __restrict__ W2,
    unsigned short* __restrict__ qo, unsigned short* __restrict__ ko, unsigned short* __restrict__ vT)
{
  __shared__ __align__(16) unsigned short smem[128*TS];   // 34816 B; reused for transpose epilogue
  unsigned short* As = smem;              // 128 x SA  (10240 B)
  unsigned short* Bs = smem + 128*SA;     // 128 x 32  (8192 B)
  int z = blockIdx.z;
  const float* X = z==0 ? X0 : (z==1 ? X1 : X2);
  const unsigned short* Wt = z==0 ? W0 : (z==1 ? W1 : W2);
  int m0 = blockIdx.y * 128, n0 = blockIdx.x * 128;
  int tid = threadIdx.x;
  int wave = tid >> 6, lane = tid & 63;
  int wrb = (wave >> 1) * 64, wcb = (wave & 1) * 64;
  int fr = lane & 15, kg = lane >> 4;

  f32x4 acc[4][4] = {};

  int arow = tid >> 3, acol = (tid & 7) * 4;
  for (int kt = 0; kt < DM/32; ++kt){
    int k0 = kt*32;
    #pragma unroll
    for (int p = 0; p < 4; ++p){                     // A: fp32 -> bf16, padded LDS
      f32x4 v = *(const f32x4*)(X + (size_t)(m0 + p*32 + arow)*DM + k0 + acol);
      u16x4 h; h[0]=f2bf(v[0]); h[1]=f2bf(v[1]); h[2]=f2bf(v[2]); h[3]=f2bf(v[3]);
      *(u16x4*)(As + (size_t)(p*32 + arow)*SA + acol) = h;
    }
    stage_gload(Wt, n0, k0, Bs, wave, lane);         // B: async to LDS
    __syncthreads();
    mma_step(As, SA, Bs, 32, wrb, wcb, fr, kg, acc);
    __syncthreads();
  }

  if (z < 2){
    unsigned short* outp = (z == 0) ? qo : ko;
    #pragma unroll
    for (int mi = 0; mi < 4; ++mi)
      #pragma unroll
      for (int ni = 0; ni < 4; ++ni){
        int r = m0 + wrb + mi*16 + kg*4;
        int c = n0 + wcb + ni*16 + fr;
        #pragma unroll
        for (int i = 0; i < 4; ++i)
          outp[(size_t)(r+i)*DM + c] = f2bf(acc[mi][ni][i]);
      }
  } else {
    unsigned short* Tt = smem;                       // [128 d][TS] holds transposed tile
    #pragma unroll
    for (int mi = 0; mi < 4; ++mi)
      #pragma unroll
      for (int ni = 0; ni < 4; ++ni){
        int rr = wrb + mi*16 + kg*4;                 // local l
        int cc = wcb + ni*16 + fr;                   // local d
        u16x4 t;
        t[0]=f2bf(acc[mi][ni][0]); t[1]=f2bf(acc[mi][ni][1]);
        t[2]=f2bf(acc[mi][ni][2]); t[3]=f2bf(acc[mi][ni][3]);
        *(u16x4*)(Tt + (size_t)cc*TS + rr) = t;
      }
    __syncthreads();
    int b = m0 >> 10, l0 = m0 & 1023;
    int dl = tid >> 1, half = tid & 1;
    unsigned short* dst = vT + ((size_t)b << 20) + (size_t)(n0 + dl)*LSEQ + l0 + half*64;
    const unsigned short* srcT = Tt + (size_t)dl*TS + half*64;
    #pragma unroll
    for (int j = 0; j < 8; ++j)
      *(u16x8*)(dst + j*8) = *(const u16x8*)(srcT + j*8);
  }
}

// ---------------- scores: S[b][q][kk] = (q . k) / 32, causal block-skip ----------------
__global__ __launch_bounds__(256) void k_scores(
    const unsigned short* __restrict__ q, const unsigned short* __restrict__ k,
    float* __restrict__ S)
{
  int b = blockIdx.z, qt = blockIdx.y, kt = blockIdx.x;
  if (kt > qt) return;                               // strictly above diagonal: never read
  __shared__ __align__(16) unsigned short As[128*32];
  __shared__ __align__(16) unsigned short Bs[128*32];
  const unsigned short* qb = q + ((size_t)b << 20);
  const unsigned short* kb = k + ((size_t)b << 20);
  int m0 = qt*128, n0 = kt*128;
  int tid = threadIdx.x, wave = tid >> 6, lane = tid & 63;
  int wrb = (wave >> 1)*64, wcb = (wave & 1)*64, fr = lane & 15, kg = lane >> 4;
  f32x4 acc[4][4] = {};
  for (int kt2 = 0; kt2 < DM/32; ++kt2){
    int k0 = kt2*32;
    stage_gload(qb, m0, k0, As, wave, lane);
    stage_gload(kb, n0, k0, Bs, wave, lane);
    __syncthreads();
    mma_step(As, 32, Bs, 32, wrb, wcb, fr, kg, acc);
    __syncthreads();
  }
  float* Sb = S + ((size_t)b << 20);
  const float scale = 0.03125f;                      // 1/sqrt(1024)
  #pragma unroll
  for (int mi = 0; mi < 4; ++mi)
    #pragma unroll
    for (int ni = 0; ni < 4; ++ni){
      int r = m0 + wrb + mi*16 + kg*4;
      int c = n0 + wcb + ni*16 + fr;
      #pragma unroll
      for (int i = 0; i < 4; ++i)
        Sb[(size_t)(r+i)*LSEQ + c] = acc[mi][ni][i] * scale;
    }
}

// ---------------- causal row softmax: P bf16, zeros above diagonal ----------------
__global__ __launch_bounds__(256) void k_softmax(
    const float* __restrict__ S, unsigned short* __restrict__ P)
{
  int gq = blockIdx.x;                                // 0..8191
  int qq = gq & 1023;
  const float* row = S + (size_t)gq * 1024;
  unsigned short* prow = P + (size_t)gq * 1024;
  int tid = threadIdx.x;

  f32x4 v = *(const f32x4*)(row + tid*4);
  float vals[4];
  float m = -1e30f;
  #pragma unroll
  for (int e = 0; e < 4; ++e){
    int idx = tid*4 + e;
    vals[e] = (idx <= qq) ? v[e] : -1e30f;
    m = fmaxf(m, vals[e]);
  }
  #pragma unroll
  for (int off = 32; off >= 1; off >>= 1) m = fmaxf(m, __shfl_xor(m, off));
  __shared__ float redm[4], reds[4];
  if ((tid & 63) == 0) redm[tid >> 6] = m;
  __syncthreads();
  m = fmaxf(fmaxf(redm[0], redm[1]), fmaxf(redm[2], redm[3]));

  float e4[4], s = 0.f;
  #pragma unroll
  for (int e = 0; e < 4; ++e){
    int idx = tid*4 + e;
    e4[e] = (idx <= qq) ? __expf(vals[e] - m) : 0.f;
    s += e4[e];
  }
  #pragma unroll
  for (int off = 32; off >= 1; off >>= 1) s += __shfl_xor(s, off);
  if ((tid & 63) == 0) reds[tid >> 6] = s;
  __syncthreads();
  s = reds[0] + reds[1] + reds[2] + reds[3];
  float inv = 1.f / s;

  u16x4 o;
  #pragma unroll
  for (int e = 0; e < 4; ++e) o[e] = f2bf(e4[e] * inv);
  *(u16x4*)(prow + tid*4) = o;
}

// ---------------- PV: O[b][q][d] = sum_kk P[q][kk] * v[kk][d], K-loop cut at diagonal ----------------
__global__ __launch_bounds__(256) void k_pv(
    const unsigned short* __restrict__ P, const unsigned short* __restrict__ vT,
    float* __restrict__ O)
{
  int b = blockIdx.z, qt = blockIdx.y, dt = blockIdx.x;
  __shared__ __align__(16) unsigned short As[128*32];
  __shared__ __align__(16) unsigned short Bs[128*32];
  const unsigned short* Pb = P  + ((size_t)b << 20);
  const unsigned short* Vb = vT + ((size_t)b << 20);
  int m0 = qt*128, n0 = dt*128;
  int tid = threadIdx.x, wave = tid >> 6, lane = tid & 63;
  int wrb = (wave >> 1)*64, wcb = (wave & 1)*64, fr = lane & 15, kg = lane >> 4;
  f32x4 acc[4][4] = {};
  int nk = (qt + 1) * 4;                              // kk in [0, (qt+1)*128)
  for (int kt = 0; kt < nk; ++kt){
    int k0 = kt*32;
    stage_gload(Pb, m0, k0, As, wave, lane);
    stage_gload(Vb, n0, k0, Bs, wave, lane);
    __syncthreads();
    mma_step(As, 32, Bs, 32, wrb, wcb, fr, kg, acc);
    __syncthreads();
  }
  float* Ob = O + ((size_t)(b*1024 + m0) << 10);
  #pragma unroll
  for (int mi = 0; mi < 4; ++mi)
    #pragma unroll
    for (int ni = 0; ni < 4; ++ni){
      int r = wrb + mi*16 + kg*4;
      int c = n0 + wcb + ni*16 + fr;
      #pragma unroll
      for (int i = 0; i < 4; ++i)
        Ob[(size_t)(r+i)*DM + c] = acc[mi][ni][i];
    }
}

extern "C" void kernel_launch(void* const* d_in, const int* in_sizes, int n_in,
                              void* d_out, int out_size, void* d_ws, size_t ws_size,
                              hipStream_t stream)
{
  const float* query = (const float*)d_in[0];
  const float* key   = (const float*)d_in[1];
  const float* value = (const float*)d_in[2];
  const float* Wq    = (const float*)d_in[3];
  const float* Wk    = (const float*)d_in[4];
  const float* Wv    = (const float*)d_in[5];
  float* out = (float*)d_out;

  unsigned short* ws = (unsigned short*)d_ws;
  unsigned short* qb  = ws;                                   // 8192x1024 bf16
  unsigned short* kb  = qb  + (size_t)MROWS*DM;
  unsigned short* vT  = kb  + (size_t)MROWS*DM;               // [B][D][L]
  unsigned short* WqT = vT  + (size_t)MROWS*DM;               // [N][K] bf16
  unsigned short* WkT = WqT + (size_t)DM*DM;
  unsigned short* WvT = WkT + (size_t)DM*DM;
  unsigned short* P   = WvT + (size_t)DM*DM;                  // [B][L][L] bf16
  float* S = out;                                             // scores staged in d_out (fp32)

  dim3 blk(256);
  k_transpose_w<<<dim3(16,16,3), blk, 0, stream>>>(Wq, Wk, Wv, WqT, WkT, WvT);
  k_proj      <<<dim3(8,64,3),  blk, 0, stream>>>(query, key, value, WqT, WkT, WvT, qb, kb, vT);
  k_scores    <<<dim3(8,8,8),   blk, 0, stream>>>(qb, kb, S);
  k_softmax   <<<dim3(8192),    blk, 0, stream>>>(S, P);
  k_pv        <<<dim3(8,8,8),   blk, 0, stream>>>(P, vT, out);
}